// Round 1
// baseline (921.961 us; speedup 1.0000x reference)
//
#include <hip/hip_runtime.h>
#include <math.h>

// Problem dims (fixed by reference)
#define NB 8
#define NT 2048
#define ND 256
#define NR (NB*NT)   // 16384 rows

__device__ __forceinline__ float dot4acc(float4 a, float4 b, float acc) {
  acc = fmaf(a.x, b.x, acc); acc = fmaf(a.y, b.y, acc);
  acc = fmaf(a.z, b.z, acc); acc = fmaf(a.w, b.w, acc);
  return acc;
}
__device__ __forceinline__ void fma4(float4& acc, float s, float4 w) {
  acc.x = fmaf(s, w.x, acc.x); acc.y = fmaf(s, w.y, acc.y);
  acc.z = fmaf(s, w.z, acc.z); acc.w = fmaf(s, w.w, acc.w);
}
__device__ __forceinline__ float sigm_(float x) { return 1.0f / (1.0f + __expf(-x)); }
__device__ __forceinline__ float tanh_(float x) { return 1.0f - 2.0f / (__expf(2.0f*x) + 1.0f); }

// ---------------------------------------------------------------------------
// prep: Wcq = Wql @ Wq_top ; per-batch fused biases for q/k/v streams.
//   biasq[b][j] = bq[j] + sum_n bql[n]*Wq[n][j] + sum_d aux[b][d]*Wq[256+d][j]
//   biask[b][j] = bk[j] + sum_d aux[b][d]*Wk[256+d][j]   (same for v)
// grid: 264 blocks x 256 threads. blocks 0..255: Wcq rows; 256..263: biases.
// ---------------------------------------------------------------------------
__global__ __launch_bounds__(256) void prep_kernel(
    const float* __restrict__ Wql, const float* __restrict__ bql,
    const float* __restrict__ Wq,  const float* __restrict__ bq,
    const float* __restrict__ Wk,  const float* __restrict__ bk,
    const float* __restrict__ Wv,  const float* __restrict__ bv,
    const float* __restrict__ aux,
    float* __restrict__ Wcq, float* __restrict__ biasq,
    float* __restrict__ biask, float* __restrict__ biasv)
{
  const int j = threadIdx.x;
  const int bid = blockIdx.x;
  if (bid < 256) {
    const int d = bid;
    float acc = 0.f;
    #pragma unroll 4
    for (int n = 0; n < 256; ++n)
      acc = fmaf(Wql[d*256 + n], Wq[n*256 + j], acc);
    Wcq[d*256 + j] = acc;
  } else {
    const int b = bid - 256;
    float accq = bq[j], acck = bk[j], accv = bv[j];
    #pragma unroll 4
    for (int n = 0; n < 256; ++n)
      accq = fmaf(bql[n], Wq[n*256 + j], accq);
    #pragma unroll 4
    for (int d = 0; d < 256; ++d) {
      const float a = aux[b*256 + d];
      accq = fmaf(a, Wq[(256 + d)*256 + j], accq);
      acck = fmaf(a, Wk[(256 + d)*256 + j], acck);
      accv = fmaf(a, Wv[(256 + d)*256 + j], accv);
    }
    biasq[b*256 + j] = accq;
    biask[b*256 + j] = acck;
    biasv[b*256 + j] = accv;
  }
}

// ---------------------------------------------------------------------------
// Fused row GEMM (16384 x 256 @ 256 x 256) + epilogue.
// MODE 0: x = in@W + bias1[b]; PReLU(alpha); LayerNorm(g,beta); *scale -> out
// MODE 1: out = sigmoid(in@W + bias1) * tanh(in@W2 + bias2)
// Block: 256 thr, 32 rows. thread: tx=t&63 -> cols 4tx..4tx+3, ty=t>>6 -> rows ty*8..+7
// ---------------------------------------------------------------------------
template<int MODE>
__global__ __launch_bounds__(256, 2) void gemm_ep(
    const float* __restrict__ in, const float* __restrict__ W,
    const float* __restrict__ W2, const float* __restrict__ bias1,
    const float* __restrict__ bias2, const float* __restrict__ aptr,
    const float* __restrict__ g, const float* __restrict__ beta,
    float* __restrict__ outp, float scale)
{
  __shared__ float As[32*260];           // padded stride 260 floats
  const int t  = threadIdx.x;
  const int tx = t & 63;
  const int ty = t >> 6;
  const int r0 = blockIdx.x * 32;
  const int b  = r0 >> 11;               // batch (2048 rows per batch)

  float4* As4 = (float4*)As;
  const float4* in4 = (const float4*)(in + (size_t)r0 * 256);
  #pragma unroll
  for (int i = 0; i < 8; ++i) {
    const int idx4 = i*256 + t;
    const int row = idx4 >> 6, c4 = idx4 & 63;
    As4[row*65 + c4] = in4[row*64 + c4];
  }
  __syncthreads();

  float4 acc[8], acc2[8];
  #pragma unroll
  for (int r = 0; r < 8; ++r) {
    acc[r]  = make_float4(0.f, 0.f, 0.f, 0.f);
    acc2[r] = make_float4(0.f, 0.f, 0.f, 0.f);
  }
  const float4* W4  = (const float4*)W;
  const float4* W24 = (const float4*)W2;

  #pragma unroll 2
  for (int k = 0; k < 256; k += 4) {
    const float4 w0 = W4[(k+0)*64 + tx];
    const float4 w1 = W4[(k+1)*64 + tx];
    const float4 w2 = W4[(k+2)*64 + tx];
    const float4 w3 = W4[(k+3)*64 + tx];
    float4 u0, u1, u2, u3;
    if (MODE == 1) {
      u0 = W24[(k+0)*64 + tx]; u1 = W24[(k+1)*64 + tx];
      u2 = W24[(k+2)*64 + tx]; u3 = W24[(k+3)*64 + tx];
    }
    #pragma unroll
    for (int r = 0; r < 8; ++r) {
      const float4 a = As4[(ty*8 + r)*65 + (k >> 2)];
      fma4(acc[r], a.x, w0); fma4(acc[r], a.y, w1);
      fma4(acc[r], a.z, w2); fma4(acc[r], a.w, w3);
      if (MODE == 1) {
        fma4(acc2[r], a.x, u0); fma4(acc2[r], a.y, u1);
        fma4(acc2[r], a.z, u2); fma4(acc2[r], a.w, u3);
      }
    }
  }

  if (MODE == 0) {
    const float alpha = aptr[0];
    const float4 bb = ((const float4*)bias1)[b*64 + tx];
    const float4 g4 = ((const float4*)g)[tx];
    const float4 be = ((const float4*)beta)[tx];
    #pragma unroll
    for (int r = 0; r < 8; ++r) {
      float4 x = acc[r];
      x.x += bb.x; x.y += bb.y; x.z += bb.z; x.w += bb.w;
      x.x = x.x >= 0.f ? x.x : alpha*x.x;
      x.y = x.y >= 0.f ? x.y : alpha*x.y;
      x.z = x.z >= 0.f ? x.z : alpha*x.z;
      x.w = x.w >= 0.f ? x.w : alpha*x.w;
      float s  = (x.x + x.y) + (x.z + x.w);
      float ss = dot4acc(x, x, 0.f);
      #pragma unroll
      for (int off = 32; off; off >>= 1) {
        s  += __shfl_xor(s,  off, 64);
        ss += __shfl_xor(ss, off, 64);
      }
      const float mean = s * (1.f/256.f);
      const float var  = ss * (1.f/256.f) - mean*mean;
      const float rstd = rsqrtf(var + 1e-5f);
      float4 o;
      o.x = ((x.x - mean)*rstd*g4.x + be.x) * scale;
      o.y = ((x.y - mean)*rstd*g4.y + be.y) * scale;
      o.z = ((x.z - mean)*rstd*g4.z + be.z) * scale;
      o.w = ((x.w - mean)*rstd*g4.w + be.w) * scale;
      ((float4*)(outp + (size_t)(r0 + ty*8 + r) * 256))[tx] = o;
    }
  } else {
    const float4 b1 = ((const float4*)bias1)[tx];
    const float4 b2 = ((const float4*)bias2)[tx];
    #pragma unroll
    for (int r = 0; r < 8; ++r) {
      float4 xs = acc[r], xt = acc2[r];
      xs.x += b1.x; xs.y += b1.y; xs.z += b1.z; xs.w += b1.w;
      xt.x += b2.x; xt.y += b2.y; xt.z += b2.z; xt.w += b2.w;
      float4 o;
      o.x = sigm_(xs.x) * tanh_(xt.x);
      o.y = sigm_(xs.y) * tanh_(xt.y);
      o.z = sigm_(xs.z) * tanh_(xt.z);
      o.w = sigm_(xs.w) * tanh_(xt.w);
      ((float4*)(outp + (size_t)(r0 + ty*8 + r) * 256))[tx] = o;
    }
  }
}

// ---------------------------------------------------------------------------
// vmean: mean over all T rows of gated v, per batch (pad-row output).
// ---------------------------------------------------------------------------
__global__ __launch_bounds__(256) void vmean_part(const float* __restrict__ vg,
                                                  float* __restrict__ part)
{
  const int bid = blockIdx.x;           // 256 = 8 batches * 32 chunks(64 rows)
  const int d = threadIdx.x;
  const int b = bid >> 5, c = bid & 31;
  const float* p = vg + ((size_t)(b*2048 + c*64)) * 256 + d;
  float s = 0.f;
  #pragma unroll 8
  for (int r = 0; r < 64; ++r) s += p[(size_t)r * 256];
  part[(size_t)bid * 256 + d] = s;
}

__global__ __launch_bounds__(256) void vmean_fin(const float* __restrict__ part,
                                                 float* __restrict__ vmean)
{
  const int b = blockIdx.x;
  const int d = threadIdx.x;
  float s = 0.f;
  #pragma unroll
  for (int c = 0; c < 32; ++c) s += part[(size_t)(b*32 + c) * 256 + d];
  vmean[b*256 + d] = s * (1.f/2048.f);
}

// ---------------------------------------------------------------------------
// Flash-style causal attention with the reference's masking quirks.
// q pre-scaled by 1/16. Block: 32 q-rows. Col tiles of 32.
// Score phase: thread(ty=t>>4, tx=t&15) owns rows {ty,ty+16} x cols {tx,tx+16}.
// PV phase:    same rows, float4-col groups {tx+16*i}, V read direct from L2.
// Pad rows (r >= len): output = vmean[b].
// ---------------------------------------------------------------------------
__global__ __launch_bounds__(256, 2) void attn_kernel(
    const float* __restrict__ q, const float* __restrict__ k,
    const float* __restrict__ v, const int* __restrict__ ilen,
    const float* __restrict__ vmean, float* __restrict__ outp)
{
  __shared__ float Qs[32*260];
  __shared__ float Ks[32*260];
  __shared__ float Ps[32*33];

  const int i = blockIdx.x;
  // pair big causal tiles with small ones on the same CU (512 blocks, 2/CU)
  const int qt = (i < 256) ? (63 - (i >> 3)) : ((i - 256) >> 3);
  const int b  = i & 7;
  const int r0 = qt * 32;
  const int len = ilen[b];
  const int t  = threadIdx.x;
  const int ty = t >> 4, tx = t & 15;

  const float4* qb4 = (const float4*)(q + (size_t)b*NT*ND);
  const float4* kb4 = (const float4*)(k + (size_t)b*NT*ND);
  const float4* vb4 = (const float4*)(v + (size_t)b*NT*ND);
  float4* out4 = (float4*)(outp + (size_t)b*NT*ND);
  const float4* vm4 = (const float4*)(vmean + b*256);

  if (r0 >= len) {          // whole tile is pad rows: uniform softmax = vmean
    #pragma unroll
    for (int it = 0; it < 8; ++it) {
      const int idx4 = it*256 + t;
      const int row = idx4 >> 6, c4 = idx4 & 63;
      out4[(size_t)(r0 + row)*64 + c4] = vm4[c4];
    }
    return;
  }

  float4* Qs4 = (float4*)Qs;
  float4* Ks4 = (float4*)Ks;
  #pragma unroll
  for (int it = 0; it < 8; ++it) {
    const int idx4 = it*256 + t;
    const int row = idx4 >> 6, c4 = idx4 & 63;
    Qs4[row*65 + c4] = qb4[(size_t)(r0 + row)*64 + c4];
  }

  float m0 = -__builtin_inff(), m1 = -__builtin_inff();
  float l0 = 0.f, l1 = 0.f;
  float4 o0[4], o1[4];
  #pragma unroll
  for (int ii = 0; ii < 4; ++ii) {
    o0[ii] = make_float4(0.f,0.f,0.f,0.f);
    o1[ii] = make_float4(0.f,0.f,0.f,0.f);
  }

  const int jmax = min(r0 + 32, len);
  const int nt = (jmax + 31) >> 5;
  const int R0 = r0 + ty, R1 = r0 + ty + 16;

  for (int tile = 0; tile < nt; ++tile) {
    const int j0 = tile << 5;
    __syncthreads();                      // prev PV done with Ps
    #pragma unroll
    for (int it = 0; it < 8; ++it) {
      const int idx4 = it*256 + t;
      const int row = idx4 >> 6, c4 = idx4 & 63;
      Ks4[row*65 + c4] = kb4[(size_t)(j0 + row)*64 + c4];
    }
    __syncthreads();

    float s00 = 0.f, s01 = 0.f, s10 = 0.f, s11 = 0.f;
    #pragma unroll 4
    for (int k4 = 0; k4 < 64; ++k4) {
      const float4 qa = Qs4[ty*65 + k4];
      const float4 qc = Qs4[(ty + 16)*65 + k4];
      const float4 ka = Ks4[tx*65 + k4];
      const float4 kc = Ks4[(tx + 16)*65 + k4];
      s00 = dot4acc(qa, ka, s00);
      s01 = dot4acc(qa, kc, s01);
      s10 = dot4acc(qc, ka, s10);
      s11 = dot4acc(qc, kc, s11);
    }

    const int C0 = j0 + tx, C1 = j0 + tx + 16;
    // mask: causal, col<len, row<len, and the "exact zero -> -inf" quirk
    const bool v00 = (C0 <= R0) && (C0 < len) && (R0 < len) && (s00 != 0.0f);
    const bool v01 = (C1 <= R0) && (C1 < len) && (R0 < len) && (s01 != 0.0f);
    const bool v10 = (C0 <= R1) && (C0 < len) && (R1 < len) && (s10 != 0.0f);
    const bool v11 = (C1 <= R1) && (C1 < len) && (R1 < len) && (s11 != 0.0f);
    s00 = v00 ? s00 : -__builtin_inff();
    s01 = v01 ? s01 : -__builtin_inff();
    s10 = v10 ? s10 : -__builtin_inff();
    s11 = v11 ? s11 : -__builtin_inff();

    // row 0 group (R0)
    float tm0 = fmaxf(s00, s01);
    #pragma unroll
    for (int off = 8; off; off >>= 1) tm0 = fmaxf(tm0, __shfl_xor(tm0, off, 16));
    const float nm0 = fmaxf(m0, tm0);
    const float f0 = (m0 == nm0) ? 1.0f : __expf(m0 - nm0);
    const float p00 = __expf(s00 - nm0);
    const float p01 = __expf(s01 - nm0);
    float sm0 = p00 + p01;
    #pragma unroll
    for (int off = 8; off; off >>= 1) sm0 += __shfl_xor(sm0, off, 16);
    l0 = l0 * f0 + sm0;
    m0 = nm0;
    #pragma unroll
    for (int ii = 0; ii < 4; ++ii) {
      o0[ii].x *= f0; o0[ii].y *= f0; o0[ii].z *= f0; o0[ii].w *= f0;
    }

    // row 1 group (R1)
    float tm1 = fmaxf(s10, s11);
    #pragma unroll
    for (int off = 8; off; off >>= 1) tm1 = fmaxf(tm1, __shfl_xor(tm1, off, 16));
    const float nm1 = fmaxf(m1, tm1);
    const float f1 = (m1 == nm1) ? 1.0f : __expf(m1 - nm1);
    const float p10 = __expf(s10 - nm1);
    const float p11 = __expf(s11 - nm1);
    float sm1 = p10 + p11;
    #pragma unroll
    for (int off = 8; off; off >>= 1) sm1 += __shfl_xor(sm1, off, 16);
    l1 = l1 * f1 + sm1;
    m1 = nm1;
    #pragma unroll
    for (int ii = 0; ii < 4; ++ii) {
      o1[ii].x *= f1; o1[ii].y *= f1; o1[ii].z *= f1; o1[ii].w *= f1;
    }

    Ps[ty*33 + tx]            = p00;
    Ps[ty*33 + tx + 16]       = p01;
    Ps[(ty + 16)*33 + tx]     = p10;
    Ps[(ty + 16)*33 + tx + 16] = p11;
    __syncthreads();

    // PV: V direct from global (L2/LLC-resident), P from LDS
    const float4* vt = vb4 + (size_t)j0 * 64;
    #pragma unroll 2
    for (int s = 0; s < 32; ++s) {
      const float p0 = Ps[ty*33 + s];
      const float p1 = Ps[(ty + 16)*33 + s];
      #pragma unroll
      for (int ii = 0; ii < 4; ++ii) {
        const float4 vv = vt[s*64 + tx + 16*ii];
        fma4(o0[ii], p0, vv);
        fma4(o1[ii], p1, vv);
      }
    }
  }

  const float i0 = 1.0f / l0;
  const float i1 = 1.0f / l1;
  #pragma unroll
  for (int ii = 0; ii < 4; ++ii) {
    const int c4 = tx + 16*ii;
    float4 w0, w1;
    if (R0 < len) {
      w0 = make_float4(o0[ii].x*i0, o0[ii].y*i0, o0[ii].z*i0, o0[ii].w*i0);
    } else {
      w0 = vm4[c4];
    }
    if (R1 < len) {
      w1 = make_float4(o1[ii].x*i1, o1[ii].y*i1, o1[ii].z*i1, o1[ii].w*i1);
    } else {
      w1 = vm4[c4];
    }
    out4[(size_t)R0*64 + c4] = w0;
    out4[(size_t)R1*64 + c4] = w1;
  }
}

// ---------------------------------------------------------------------------
extern "C" void kernel_launch(void* const* d_in, const int* in_sizes, int n_in,
                              void* d_out, int out_size, void* d_ws, size_t ws_size,
                              hipStream_t stream) {
  const float* query = (const float*)d_in[0];
  const float* value = (const float*)d_in[1];
  const float* aux   = (const float*)d_in[2];
  const int*   ilen  = (const int*)  d_in[3];
  const float* Wql = (const float*)d_in[4];
  const float* bql = (const float*)d_in[5];
  const float* Wq  = (const float*)d_in[6];
  const float* bq  = (const float*)d_in[7];
  const float* aq  = (const float*)d_in[8];
  const float* gq  = (const float*)d_in[9];
  const float* btq = (const float*)d_in[10];
  const float* Wk  = (const float*)d_in[11];
  const float* bk  = (const float*)d_in[12];
  const float* ak  = (const float*)d_in[13];
  const float* gk  = (const float*)d_in[14];
  const float* btk = (const float*)d_in[15];
  const float* Wv  = (const float*)d_in[16];
  const float* bv  = (const float*)d_in[17];
  const float* av  = (const float*)d_in[18];
  const float* gv  = (const float*)d_in[19];
  const float* btv = (const float*)d_in[20];
  const float* Ws  = (const float*)d_in[21];
  const float* bs  = (const float*)d_in[22];
  const float* Wt  = (const float*)d_in[23];
  const float* bt  = (const float*)d_in[24];

  float* wsf = (float*)d_ws;
  float* qbuf  = wsf;                    // 16384*256
  float* kbuf  = qbuf  + (size_t)NR*ND;
  float* vln   = kbuf  + (size_t)NR*ND;
  float* vg    = vln   + (size_t)NR*ND;
  float* Wcq   = vg    + (size_t)NR*ND;  // 256*256
  float* biasq = Wcq   + 256*256;        // 8*256 each
  float* biask = biasq + NB*ND;
  float* biasv = biask + NB*ND;
  float* part  = biasv + NB*ND;          // 256*256
  float* vmean = part  + 256*256;        // 8*256

  prep_kernel<<<dim3(264), dim3(256), 0, stream>>>(
      Wql, bql, Wq, bq, Wk, bk, Wv, bv, aux, Wcq, biasq, biask, biasv);

  // q = LN(PReLU(query@Wcq + biasq)) * (1/16)   (score scale folded in)
  gemm_ep<0><<<dim3(NR/32), dim3(256), 0, stream>>>(
      query, Wcq, nullptr, biasq, nullptr, aq, gq, btq, qbuf, 0.0625f);
  // k = LN(PReLU(value@Wk_top + biask))   (Wk_top = first 256 rows of Wk)
  gemm_ep<0><<<dim3(NR/32), dim3(256), 0, stream>>>(
      value, Wk, nullptr, biask, nullptr, ak, gk, btk, kbuf, 1.0f);
  // v_ln = LN(PReLU(value@Wv_top + biasv))
  gemm_ep<0><<<dim3(NR/32), dim3(256), 0, stream>>>(
      value, Wv, nullptr, biasv, nullptr, av, gv, btv, vln, 1.0f);
  // v = sigmoid(v_ln@Ws + bs) * tanh(v_ln@Wt + bt)
  gemm_ep<1><<<dim3(NR/32), dim3(256), 0, stream>>>(
      vln, Ws, Wt, bs, bt, aq, gq, btq, vg, 1.0f);

  vmean_part<<<dim3(256), dim3(256), 0, stream>>>(vg, part);
  vmean_fin<<<dim3(8), dim3(256), 0, stream>>>(part, vmean);

  attn_kernel<<<dim3(512), dim3(256), 0, stream>>>(
      qbuf, kbuf, vg, ilen, vmean, (float*)d_out);
}

// Round 2
// 448.897 us; speedup vs baseline: 2.0538x; 2.0538x over previous
//
#include <hip/hip_runtime.h>
#include <math.h>

#define NB 8
#define NT 2048
#define ND 256
#define NR (NB*NT)   // 16384 rows

typedef __attribute__((ext_vector_type(8))) short bf16x8;
typedef __attribute__((ext_vector_type(4))) float f32x4;

// log2(e)/16 : folds both 1/sqrt(256) and the exp->exp2 conversion into q
#define QSCALE 0.09016844005556021f

__device__ __forceinline__ float dot4acc(float4 a, float4 b, float acc) {
  acc = fmaf(a.x, b.x, acc); acc = fmaf(a.y, b.y, acc);
  acc = fmaf(a.z, b.z, acc); acc = fmaf(a.w, b.w, acc);
  return acc;
}
__device__ __forceinline__ void fma4(float4& acc, float s, float4 w) {
  acc.x = fmaf(s, w.x, acc.x); acc.y = fmaf(s, w.y, acc.y);
  acc.z = fmaf(s, w.z, acc.z); acc.w = fmaf(s, w.w, acc.w);
}
__device__ __forceinline__ float sigm_(float x) { return 1.0f / (1.0f + __expf(-x)); }
__device__ __forceinline__ float tanh_(float x) { return 1.0f - 2.0f / (__expf(2.0f*x) + 1.0f); }
__device__ __forceinline__ unsigned short f2bf(float x) {
  union { float f; unsigned u; } v; v.f = x;
  unsigned r = v.u + 0x7fffu + ((v.u >> 16) & 1u);   // RNE (finite inputs only)
  return (unsigned short)(r >> 16);
}

// ---------------------------------------------------------------------------
// prep: Wcq = Wql @ Wq_top ; per-batch fused biases for q/k/v streams.
// ---------------------------------------------------------------------------
__global__ __launch_bounds__(256) void prep_kernel(
    const float* __restrict__ Wql, const float* __restrict__ bql,
    const float* __restrict__ Wq,  const float* __restrict__ bq,
    const float* __restrict__ Wk,  const float* __restrict__ bk,
    const float* __restrict__ Wv,  const float* __restrict__ bv,
    const float* __restrict__ aux,
    float* __restrict__ Wcq, float* __restrict__ biasq,
    float* __restrict__ biask, float* __restrict__ biasv)
{
  const int j = threadIdx.x;
  const int bid = blockIdx.x;
  if (bid < 256) {
    const int d = bid;
    float acc = 0.f;
    #pragma unroll 4
    for (int n = 0; n < 256; ++n)
      acc = fmaf(Wql[d*256 + n], Wq[n*256 + j], acc);
    Wcq[d*256 + j] = acc;
  } else {
    const int b = bid - 256;
    float accq = bq[j], acck = bk[j], accv = bv[j];
    #pragma unroll 4
    for (int n = 0; n < 256; ++n)
      accq = fmaf(bql[n], Wq[n*256 + j], accq);
    #pragma unroll 4
    for (int d = 0; d < 256; ++d) {
      const float a = aux[b*256 + d];
      accq = fmaf(a, Wq[(256 + d)*256 + j], accq);
      acck = fmaf(a, Wk[(256 + d)*256 + j], acck);
      accv = fmaf(a, Wv[(256 + d)*256 + j], accv);
    }
    biasq[b*256 + j] = accq;
    biask[b*256 + j] = acck;
    biasv[b*256 + j] = accv;
  }
}

// ---------------------------------------------------------------------------
// Fused row GEMM (16384 x 256 @ 256 x 256) + epilogue.
// MODE 0: x = in@W + bias1[b]; PReLU; LayerNorm; *scale. OB=1 -> bf16 output.
// MODE 1: out = sigmoid(in@W + bias1) * tanh(in@W2 + bias2), fp32 out.
// ---------------------------------------------------------------------------
template<int MODE, int OB>
__global__ __launch_bounds__(256, 2) void gemm_ep(
    const float* __restrict__ in, const float* __restrict__ W,
    const float* __restrict__ W2, const float* __restrict__ bias1,
    const float* __restrict__ bias2, const float* __restrict__ aptr,
    const float* __restrict__ g, const float* __restrict__ beta,
    void* __restrict__ outp, float scale)
{
  __shared__ float As[32*260];
  const int t  = threadIdx.x;
  const int tx = t & 63;
  const int ty = t >> 6;
  const int r0 = blockIdx.x * 32;
  const int b  = r0 >> 11;

  float4* As4 = (float4*)As;
  const float4* in4 = (const float4*)(in + (size_t)r0 * 256);
  #pragma unroll
  for (int i = 0; i < 8; ++i) {
    const int idx4 = i*256 + t;
    const int row = idx4 >> 6, c4 = idx4 & 63;
    As4[row*65 + c4] = in4[row*64 + c4];
  }
  __syncthreads();

  float4 acc[8], acc2[8];
  #pragma unroll
  for (int r = 0; r < 8; ++r) {
    acc[r]  = make_float4(0.f, 0.f, 0.f, 0.f);
    acc2[r] = make_float4(0.f, 0.f, 0.f, 0.f);
  }
  const float4* W4  = (const float4*)W;
  const float4* W24 = (const float4*)W2;

  #pragma unroll 2
  for (int k = 0; k < 256; k += 4) {
    const float4 w0 = W4[(k+0)*64 + tx];
    const float4 w1 = W4[(k+1)*64 + tx];
    const float4 w2 = W4[(k+2)*64 + tx];
    const float4 w3 = W4[(k+3)*64 + tx];
    float4 u0, u1, u2, u3;
    if (MODE == 1) {
      u0 = W24[(k+0)*64 + tx]; u1 = W24[(k+1)*64 + tx];
      u2 = W24[(k+2)*64 + tx]; u3 = W24[(k+3)*64 + tx];
    }
    #pragma unroll
    for (int r = 0; r < 8; ++r) {
      const float4 a = As4[(ty*8 + r)*65 + (k >> 2)];
      fma4(acc[r], a.x, w0); fma4(acc[r], a.y, w1);
      fma4(acc[r], a.z, w2); fma4(acc[r], a.w, w3);
      if (MODE == 1) {
        fma4(acc2[r], a.x, u0); fma4(acc2[r], a.y, u1);
        fma4(acc2[r], a.z, u2); fma4(acc2[r], a.w, u3);
      }
    }
  }

  if (MODE == 0) {
    const float alpha = aptr[0];
    const float4 bb = ((const float4*)bias1)[b*64 + tx];
    const float4 g4 = ((const float4*)g)[tx];
    const float4 be = ((const float4*)beta)[tx];
    #pragma unroll
    for (int r = 0; r < 8; ++r) {
      float4 x = acc[r];
      x.x += bb.x; x.y += bb.y; x.z += bb.z; x.w += bb.w;
      x.x = x.x >= 0.f ? x.x : alpha*x.x;
      x.y = x.y >= 0.f ? x.y : alpha*x.y;
      x.z = x.z >= 0.f ? x.z : alpha*x.z;
      x.w = x.w >= 0.f ? x.w : alpha*x.w;
      float s  = (x.x + x.y) + (x.z + x.w);
      float ss = dot4acc(x, x, 0.f);
      #pragma unroll
      for (int off = 32; off; off >>= 1) {
        s  += __shfl_xor(s,  off, 64);
        ss += __shfl_xor(ss, off, 64);
      }
      const float mean = s * (1.f/256.f);
      const float var  = ss * (1.f/256.f) - mean*mean;
      const float rstd = rsqrtf(var + 1e-5f);
      float4 o;
      o.x = ((x.x - mean)*rstd*g4.x + be.x) * scale;
      o.y = ((x.y - mean)*rstd*g4.y + be.y) * scale;
      o.z = ((x.z - mean)*rstd*g4.z + be.z) * scale;
      o.w = ((x.w - mean)*rstd*g4.w + be.w) * scale;
      if (OB) {
        ushort4 u;
        u.x = f2bf(o.x); u.y = f2bf(o.y); u.z = f2bf(o.z); u.w = f2bf(o.w);
        *(ushort4*)((unsigned short*)outp + (size_t)(r0 + ty*8 + r) * 256 + tx*4) = u;
      } else {
        ((float4*)((float*)outp + (size_t)(r0 + ty*8 + r) * 256))[tx] = o;
      }
    }
  } else {
    const float4 b1 = ((const float4*)bias1)[tx];
    const float4 b2 = ((const float4*)bias2)[tx];
    #pragma unroll
    for (int r = 0; r < 8; ++r) {
      float4 xs = acc[r], xt = acc2[r];
      xs.x += b1.x; xs.y += b1.y; xs.z += b1.z; xs.w += b1.w;
      xt.x += b2.x; xt.y += b2.y; xt.z += b2.z; xt.w += b2.w;
      float4 o;
      o.x = sigm_(xs.x) * tanh_(xt.x);
      o.y = sigm_(xs.y) * tanh_(xt.y);
      o.z = sigm_(xs.z) * tanh_(xt.z);
      o.w = sigm_(xs.w) * tanh_(xt.w);
      ((float4*)((float*)outp + (size_t)(r0 + ty*8 + r) * 256))[tx] = o;
    }
  }
}

// ---------------------------------------------------------------------------
// vmean: mean over all T rows of gated v, per batch (pad-row output).
// ---------------------------------------------------------------------------
__global__ __launch_bounds__(256) void vmean_part(const float* __restrict__ vg,
                                                  float* __restrict__ part)
{
  const int bid = blockIdx.x;
  const int d = threadIdx.x;
  const int b = bid >> 5, c = bid & 31;
  const float* p = vg + ((size_t)(b*2048 + c*64)) * 256 + d;
  float s = 0.f;
  #pragma unroll 8
  for (int r = 0; r < 64; ++r) s += p[(size_t)r * 256];
  part[(size_t)bid * 256 + d] = s;
}

__global__ __launch_bounds__(256) void vmean_fin(const float* __restrict__ part,
                                                 float* __restrict__ vmean)
{
  const int b = blockIdx.x;
  const int d = threadIdx.x;
  float s = 0.f;
  #pragma unroll
  for (int c = 0; c < 32; ++c) s += part[(size_t)(b*32 + c) * 256 + d];
  vmean[b*256 + d] = s * (1.f/2048.f);
}

// ---------------------------------------------------------------------------
// transpose_v: vg fp32 [b][t][d] -> Vt bf16 [b][d][t].  64x64 tiles.
// grid (32, 4, 8) x 256 thr. LDS stride 68 dwords (b128-aligned, low conflict).
// ---------------------------------------------------------------------------
__global__ __launch_bounds__(256) void transpose_v(const float* __restrict__ vg,
                                                   unsigned short* __restrict__ Vt)
{
  __shared__ float Ld[64*68];
  const int b  = blockIdx.z;
  const int t0 = blockIdx.x * 64;
  const int d0 = blockIdx.y * 64;
  const int tid = threadIdx.x;
  const int c4 = tid & 15, r = tid >> 4;
  #pragma unroll
  for (int i = 0; i < 4; ++i) {
    const int row = r + 16*i;
    float4 v = *(const float4*)(vg + ((size_t)(b*NT + t0 + row))*ND + d0 + c4*4);
    *(float4*)(Ld + row*68 + c4*4) = v;
  }
  __syncthreads();
  const int d = tid >> 2, part = tid & 3;
  unsigned out[8];
  #pragma unroll
  for (int j = 0; j < 8; ++j) {
    const int t2 = part*8 + j;
    const float lo = Ld[(2*t2)*68 + d];
    const float hi = Ld[(2*t2 + 1)*68 + d];
    out[j] = (unsigned)f2bf(lo) | ((unsigned)f2bf(hi) << 16);
  }
  unsigned short* op = Vt + ((size_t)(b*ND + d0 + d))*NT + t0 + part*16;
  *(uint4*)(op)     = make_uint4(out[0], out[1], out[2], out[3]);
  *(uint4*)(op + 8) = make_uint4(out[4], out[5], out[6], out[7]);
}

// ---------------------------------------------------------------------------
// attn_mfma: flash attention, bf16 MFMA 16x16x32, fp32 softmax (log2 domain).
// 2048 waves; wave g -> unit i=g>>1 (heavy/light paired per block), half=g&1.
// Per wave: 16 q-rows, col-tiles of 32 over its half of the causal range.
// Q/K/V frags loaded directly from global in fragment layout (L2-resident).
// P goes C-layout -> A-layout through a 1KB per-wave swizzled LDS bounce.
// Partials (m,l,O) written per wave; attn_merge combines the two halves.
// ---------------------------------------------------------------------------
__global__ __launch_bounds__(256, 2) void attn_mfma(
    const unsigned short* __restrict__ qb, const unsigned short* __restrict__ kb,
    const unsigned short* __restrict__ Vt, const int* __restrict__ ilen,
    float* __restrict__ pm, float* __restrict__ pl, float* __restrict__ pO)
{
  __shared__ unsigned short Ps[4][512];
  const int w = threadIdx.x >> 6, lane = threadIdx.x & 63;
  const int g = blockIdx.x*4 + w;
  const int i = g >> 1, half = g & 1;
  const int pp = i >> 1, s = i & 1;
  const int qt = s ? 127 - (pp >> 2) : (pp >> 2);
  const int b  = ((pp & 3) << 1) | s;
  const int r0 = qt << 4;
  const int len = ilen[b];
  if (r0 >= len) return;                  // pad-only unit: merge emits vmean
  const int jmax = min(r0 + 16, len);
  const int nt = (jmax + 31) >> 5;
  const int nh = (nt + 1) >> 1;
  const int tb = half ? nh : 0, te = half ? nt : nh;

  const int fc = lane & 15;               // frag col index (A-row / B-col / C-col)
  const int sl = lane >> 4;               // k-slice / C row group

  bf16x8 aq[8];
  {
    const unsigned short* qp = qb + ((size_t)(b*NT + r0 + fc))*ND + sl*8;
    #pragma unroll
    for (int c = 0; c < 8; ++c) aq[c] = *(const bf16x8*)(qp + c*32);
  }

  f32x4 O[16];
  #pragma unroll
  for (int dc = 0; dc < 16; ++dc) O[dc] = (f32x4)(0.f);
  float m_[4], l_[4];
  #pragma unroll
  for (int r = 0; r < 4; ++r) { m_[r] = -__builtin_inff(); l_[r] = 0.f; }

  const unsigned short* kbase = kb + (size_t)b*NT*ND;
  const unsigned short* vbase = Vt + (size_t)b*ND*NT;
  unsigned short* psw = &Ps[w][0];

  for (int t = tb; t < te; ++t) {
    const int j0 = t << 5;
    // ---- QK^T: S[16q x 32k] (two 16-col frags) ----
    f32x4 S0 = (f32x4)(0.f), S1 = (f32x4)(0.f);
    const unsigned short* kp0 = kbase + ((size_t)(j0 + fc))*ND + sl*8;
    #pragma unroll
    for (int c = 0; c < 8; ++c) {
      bf16x8 b0 = *(const bf16x8*)(kp0 + c*32);
      bf16x8 b1 = *(const bf16x8*)(kp0 + (size_t)16*ND + c*32);
      S0 = __builtin_amdgcn_mfma_f32_16x16x32_bf16(aq[c], b0, S0, 0, 0, 0);
      S1 = __builtin_amdgcn_mfma_f32_16x16x32_bf16(aq[c], b1, S1, 0, 0, 0);
    }
    // prefetch first 8 V frags (hide L2 latency under softmax VALU)
    bf16x8 bv[8];
    #pragma unroll
    for (int dc = 0; dc < 8; ++dc)
      bv[dc] = *(const bf16x8*)(vbase + ((size_t)(dc*16 + fc))*NT + j0 + sl*8);

    // ---- mask (causal + row<len + exact-zero quirk); S is in log2 units ----
    const int C0 = j0 + fc, C1 = C0 + 16;
    const int Rb = r0 + sl*4;
    float s0[4], s1[4];
    #pragma unroll
    for (int r = 0; r < 4; ++r) {
      const int R = Rb + r;
      const bool okR = (R < len);
      const float x0 = S0[r], x1 = S1[r];
      s0[r] = (okR && (C0 <= R) && (x0 != 0.f)) ? x0 : -__builtin_inff();
      s1[r] = (okR && (C1 <= R) && (x1 != 0.f)) ? x1 : -__builtin_inff();
    }
    // ---- row max over 16 lanes ----
    float tm[4];
    #pragma unroll
    for (int r = 0; r < 4; ++r) tm[r] = fmaxf(s0[r], s1[r]);
    #pragma unroll
    for (int off = 1; off < 16; off <<= 1) {
      #pragma unroll
      for (int r = 0; r < 4; ++r) tm[r] = fmaxf(tm[r], __shfl_xor(tm[r], off, 16));
    }
    // ---- defer-max rescale ----
    bool need = false;
    #pragma unroll
    for (int r = 0; r < 4; ++r) need |= (tm[r] > m_[r] + 8.f);
    if (__any(need)) {
      #pragma unroll
      for (int r = 0; r < 4; ++r) {
        const float nm = fmaxf(m_[r], tm[r]);
        const float f = (m_[r] == nm) ? 1.f : exp2f(m_[r] - nm);
        m_[r] = nm; l_[r] *= f;
        #pragma unroll
        for (int dc = 0; dc < 16; ++dc) O[dc][r] *= f;
      }
    }
    // ---- p = 2^(S - m), row-sum into l ----
    float p0[4], p1[4], ps[4];
    #pragma unroll
    for (int r = 0; r < 4; ++r) {
      p0[r] = (s0[r] == -__builtin_inff()) ? 0.f : exp2f(s0[r] - m_[r]);
      p1[r] = (s1[r] == -__builtin_inff()) ? 0.f : exp2f(s1[r] - m_[r]);
      ps[r] = p0[r] + p1[r];
    }
    #pragma unroll
    for (int off = 1; off < 16; off <<= 1) {
      #pragma unroll
      for (int r = 0; r < 4; ++r) ps[r] += __shfl_xor(ps[r], off, 16);
    }
    #pragma unroll
    for (int r = 0; r < 4; ++r) l_[r] += ps[r];
    // ---- P: C-layout -> bf16 A-frag via swizzled per-wave LDS (no barrier) ----
    #pragma unroll
    for (int r = 0; r < 4; ++r) {
      const int q = sl*4 + r;
      const int sw = (q & 7) << 3;   // short-index XOR (16B-granular in bytes)
      psw[(q*32 + fc) ^ sw]      = f2bf(p0[r]);
      psw[(q*32 + fc + 16) ^ sw] = f2bf(p1[r]);
    }
    const bf16x8 pa = *(const bf16x8*)&psw[(fc*32 + sl*8) ^ ((fc & 7) << 3)];
    // ---- PV: O[16q x 256d] += P x V ----
    #pragma unroll
    for (int dc = 0; dc < 8; ++dc)
      O[dc] = __builtin_amdgcn_mfma_f32_16x16x32_bf16(pa, bv[dc], O[dc], 0, 0, 0);
    #pragma unroll
    for (int dc = 8; dc < 16; ++dc) {
      const bf16x8 bvv = *(const bf16x8*)(vbase + ((size_t)(dc*16 + fc))*NT + j0 + sl*8);
      O[dc] = __builtin_amdgcn_mfma_f32_16x16x32_bf16(pa, bvv, O[dc], 0, 0, 0);
    }
  }

  // ---- write partials ----
  if (fc == 0) {
    #pragma unroll
    for (int r = 0; r < 4; ++r) {
      pm[g*16 + sl*4 + r] = m_[r];
      pl[g*16 + sl*4 + r] = l_[r];
    }
  }
  if (tb < te) {
    float* po = pO + (size_t)g * 4096;
    #pragma unroll
    for (int dc = 0; dc < 16; ++dc) {
      #pragma unroll
      for (int r = 0; r < 4; ++r)
        po[(sl*4 + r)*256 + dc*16 + fc] = O[dc][r];
    }
  }
}

// ---------------------------------------------------------------------------
// attn_merge: combine the two half-partials of each unit; pad rows -> vmean.
// grid 1024 blocks (one per unit) x 256 thr (16 rows x 16 d-groups).
// ---------------------------------------------------------------------------
__global__ __launch_bounds__(256) void attn_merge(
    const float* __restrict__ pm, const float* __restrict__ pl,
    const float* __restrict__ pO, const float* __restrict__ vmean,
    const int* __restrict__ ilen, float* __restrict__ outp)
{
  const int i = blockIdx.x;
  const int pp = i >> 1, s = i & 1;
  const int qt = s ? 127 - (pp >> 2) : (pp >> 2);
  const int b  = ((pp & 3) << 1) | s;
  const int r0 = qt << 4;
  const int len = ilen[b];
  const int t = threadIdx.x;
  const int row = t >> 4, d0 = (t & 15) << 4;
  const int rowg = r0 + row;
  float4* o4 = (float4*)(outp + ((size_t)(b*NT + rowg))*ND + d0);
  if (rowg >= len) {
    const float4* vm4 = (const float4*)(vmean + b*ND + d0);
    #pragma unroll
    for (int ii = 0; ii < 4; ++ii) o4[ii] = vm4[ii];
    return;
  }
  const int g0 = 2*i, g1 = 2*i + 1;
  const float m0 = pm[g0*16 + row], m1 = pm[g1*16 + row];
  const float l0 = pl[g0*16 + row], l1 = pl[g1*16 + row];
  const float M = fmaxf(m0, m1);
  float w0 = (m0 == -__builtin_inff()) ? 0.f : exp2f(m0 - M);
  float w1 = (m1 == -__builtin_inff()) ? 0.f : exp2f(m1 - M);
  const float inv = 1.f / (w0*l0 + w1*l1);
  w0 *= inv; w1 *= inv;
  const float4* a4 = (const float4*)(pO + (size_t)g0*4096 + row*256 + d0);
  const float4* b4 = (const float4*)(pO + (size_t)g1*4096 + row*256 + d0);
  #pragma unroll
  for (int ii = 0; ii < 4; ++ii) {
    float4 av = a4[ii], bv = b4[ii], ov;
    ov.x = av.x*w0 + bv.x*w1;
    ov.y = av.y*w0 + bv.y*w1;
    ov.z = av.z*w0 + bv.z*w1;
    ov.w = av.w*w0 + bv.w*w1;
    o4[ii] = ov;
  }
}

// ---------------------------------------------------------------------------
extern "C" void kernel_launch(void* const* d_in, const int* in_sizes, int n_in,
                              void* d_out, int out_size, void* d_ws, size_t ws_size,
                              hipStream_t stream) {
  const float* query = (const float*)d_in[0];
  const float* value = (const float*)d_in[1];
  const float* aux   = (const float*)d_in[2];
  const int*   ilen  = (const int*)  d_in[3];
  const float* Wql = (const float*)d_in[4];
  const float* bql = (const float*)d_in[5];
  const float* Wq  = (const float*)d_in[6];
  const float* bq  = (const float*)d_in[7];
  const float* aq  = (const float*)d_in[8];
  const float* gq  = (const float*)d_in[9];
  const float* btq = (const float*)d_in[10];
  const float* Wk  = (const float*)d_in[11];
  const float* bk  = (const float*)d_in[12];
  const float* ak  = (const float*)d_in[13];
  const float* gk  = (const float*)d_in[14];
  const float* btk = (const float*)d_in[15];
  const float* Wv  = (const float*)d_in[16];
  const float* bv  = (const float*)d_in[17];
  const float* av  = (const float*)d_in[18];
  const float* gv  = (const float*)d_in[19];
  const float* btv = (const float*)d_in[20];
  const float* Ws  = (const float*)d_in[21];
  const float* bs  = (const float*)d_in[22];
  const float* Wt  = (const float*)d_in[23];
  const float* bt  = (const float*)d_in[24];

  float* wsf = (float*)d_ws;
  // bf16 buffers occupy half the floats
  unsigned short* qbuf = (unsigned short*)wsf;                    // NR*ND bf16
  unsigned short* kbuf = (unsigned short*)(wsf + (size_t)NR*ND/2);
  float* vln   = wsf + (size_t)NR*ND;                             // NR*ND fp32
  float* vg    = vln + (size_t)NR*ND;                             // NR*ND fp32
  float* pO    = vln;                                             // overlay: 2048*4096 = 2*NR*ND floats
  unsigned short* Vt = (unsigned short*)(vg + (size_t)NR*ND);     // NR*ND bf16
  float* Wcq   = (float*)(Vt) + (size_t)NR*ND/2;
  float* biasq = Wcq   + 256*256;
  float* biask = biasq + NB*ND;
  float* biasv = biask + NB*ND;
  float* part  = biasv + NB*ND;
  float* vmean = part  + 256*256;
  float* pm    = vmean + NB*ND;          // 2048*16
  float* pl    = pm + 2048*16;           // 2048*16

  prep_kernel<<<dim3(264), dim3(256), 0, stream>>>(
      Wql, bql, Wq, bq, Wk, bk, Wv, bv, aux, Wcq, biasq, biask, biasv);

  // q = LN(PReLU(query@Wcq + biasq)) * log2(e)/16  -> bf16
  gemm_ep<0,1><<<dim3(NR/32), dim3(256), 0, stream>>>(
      query, Wcq, nullptr, biasq, nullptr, aq, gq, btq, qbuf, QSCALE);
  // k -> bf16
  gemm_ep<0,1><<<dim3(NR/32), dim3(256), 0, stream>>>(
      value, Wk, nullptr, biask, nullptr, ak, gk, btk, kbuf, 1.0f);
  // v_ln fp32
  gemm_ep<0,0><<<dim3(NR/32), dim3(256), 0, stream>>>(
      value, Wv, nullptr, biasv, nullptr, av, gv, btv, vln, 1.0f);
  // v gated fp32
  gemm_ep<1,0><<<dim3(NR/32), dim3(256), 0, stream>>>(
      vln, Ws, Wt, bs, bt, aq, gq, btq, vg, 1.0f);

  vmean_part<<<dim3(256), dim3(256), 0, stream>>>(vg, part);
  vmean_fin<<<dim3(8), dim3(256), 0, stream>>>(part, vmean);

  transpose_v<<<dim3(32, 4, 8), dim3(256), 0, stream>>>(vg, Vt);

  // NOTE: pO overlays vln/vg — attn runs after transpose+vmean (stream-ordered)
  attn_mfma<<<dim3(512), dim3(256), 0, stream>>>(
      qbuf, kbuf, Vt, ilen, pm, pl, pO);

  attn_merge<<<dim3(1024), dim3(256), 0, stream>>>(
      pm, pl, pO, vmean, ilen, (float*)d_out);
}

// Round 3
// 414.357 us; speedup vs baseline: 2.2250x; 1.0834x over previous
//
#include <hip/hip_runtime.h>
#include <math.h>

#define NB 8
#define NT 2048
#define ND 256
#define NR (NB*NT)   // 16384 rows

typedef _Float16 f16x8 __attribute__((ext_vector_type(8)));
typedef _Float16 f16x4 __attribute__((ext_vector_type(4)));
typedef float f32x4 __attribute__((ext_vector_type(4)));

// log2(e)/16 : folds 1/sqrt(256) and exp->exp2 into q
#define QSCALE 0.09016844005556021f
// fixed softmax max (log2 domain). |s| <= 23 hard bound (LN norms = 16) -> p <= 2^15 fits f16.
#define MFIX 8.0f

__device__ __forceinline__ float sigm_(float x) { return 1.0f / (1.0f + __expf(-x)); }
__device__ __forceinline__ float tanh_(float x) { return 1.0f - 2.0f / (__expf(2.0f*x) + 1.0f); }

// ---------------------------------------------------------------------------
// prep: Wcq = Wql @ Wq_top (fp32); per-batch fused biases; zero vmean.
// ---------------------------------------------------------------------------
__global__ __launch_bounds__(256) void prep_kernel(
    const float* __restrict__ Wql, const float* __restrict__ bql,
    const float* __restrict__ Wq,  const float* __restrict__ bq,
    const float* __restrict__ Wk,  const float* __restrict__ bk,
    const float* __restrict__ Wv,  const float* __restrict__ bv,
    const float* __restrict__ aux,
    float* __restrict__ Wcq, float* __restrict__ biasq,
    float* __restrict__ biask, float* __restrict__ biasv,
    float* __restrict__ vmean)
{
  const int j = threadIdx.x;
  const int bid = blockIdx.x;
  if (bid < 256) {
    const int d = bid;
    float acc = 0.f;
    #pragma unroll 4
    for (int n = 0; n < 256; ++n)
      acc = fmaf(Wql[d*256 + n], Wq[n*256 + j], acc);
    Wcq[d*256 + j] = acc;
  } else {
    const int b = bid - 256;
    float accq = bq[j], acck = bk[j], accv = bv[j];
    #pragma unroll 4
    for (int n = 0; n < 256; ++n)
      accq = fmaf(bql[n], Wq[n*256 + j], accq);
    #pragma unroll 4
    for (int d = 0; d < 256; ++d) {
      const float a = aux[b*256 + d];
      accq = fmaf(a, Wq[(256 + d)*256 + j], accq);
      acck = fmaf(a, Wk[(256 + d)*256 + j], acck);
      accv = fmaf(a, Wv[(256 + d)*256 + j], accv);
    }
    biasq[b*256 + j] = accq;
    biask[b*256 + j] = acck;
    biasv[b*256 + j] = accv;
    vmean[b*256 + j] = 0.f;
  }
}

// ---------------------------------------------------------------------------
// transW: WT[z][n][k] = f16(W_z[k][n]) for z in {Wcq, Wk_top, Wv_top, Ws, Wt}.
// grid (4,4,5) x 256 thr; 64x64 tiles via LDS.
// ---------------------------------------------------------------------------
__global__ __launch_bounds__(256) void transW(
    const float* __restrict__ Wcq, const float* __restrict__ Wk,
    const float* __restrict__ Wv,  const float* __restrict__ Ws,
    const float* __restrict__ Wt,  _Float16* __restrict__ WT)
{
  __shared__ float Ld[64*68];
  const int z = blockIdx.z;
  const float* src = (z==0) ? Wcq : (z==1) ? Wk : (z==2) ? Wv : (z==3) ? Ws : Wt;
  _Float16* dst = WT + (size_t)z*65536;
  const int k0 = blockIdx.x*64, n0 = blockIdx.y*64;
  const int tid = threadIdx.x;
  const int c4 = tid & 15, r = tid >> 4;
  #pragma unroll
  for (int i = 0; i < 4; ++i) {
    const int row = r + 16*i;
    float4 v = *(const float4*)(src + (size_t)(k0 + row)*256 + n0 + c4*4);
    *(float4*)(Ld + row*68 + c4*4) = v;
  }
  __syncthreads();
  const int nl = tid >> 2, part = tid & 3;
  f16x8 lo, hi;
  #pragma unroll
  for (int j = 0; j < 8; ++j) lo[j] = (_Float16)Ld[(part*16 + j)*68 + nl];
  #pragma unroll
  for (int j = 0; j < 8; ++j) hi[j] = (_Float16)Ld[(part*16 + 8 + j)*68 + nl];
  _Float16* op = dst + (size_t)(n0 + nl)*256 + k0 + part*16;
  *(f16x8*)(op)     = lo;
  *(f16x8*)(op + 8) = hi;
}

// ---------------------------------------------------------------------------
// gemm_m0: out = f16( (LN(PReLU(in@W + bias[b])) * g + beta) * scale )
// 1 wave per block; wave = 16 rows x 256 cols; MFMA f16 16x16x32.
// in fp32 row-major [16384][256]; WT f16 [N=256][K=256].
// ---------------------------------------------------------------------------
__global__ __launch_bounds__(64) void gemm_m0(
    const float* __restrict__ in, const _Float16* __restrict__ WT,
    const float* __restrict__ bias, const float* __restrict__ aptr,
    const float* __restrict__ g, const float* __restrict__ beta,
    _Float16* __restrict__ out, float scale)
{
  const int lane = threadIdx.x;
  const int fc = lane & 15, sl = lane >> 4;
  const int r0 = blockIdx.x * 16;
  const int b = r0 >> 11;

  f16x8 a[8];
  const float* ap = in + (size_t)(r0 + fc)*256 + sl*8;
  #pragma unroll
  for (int c = 0; c < 8; ++c) {
    const float4 x0 = *(const float4*)(ap + c*32);
    const float4 x1 = *(const float4*)(ap + c*32 + 4);
    a[c][0] = (_Float16)x0.x; a[c][1] = (_Float16)x0.y;
    a[c][2] = (_Float16)x0.z; a[c][3] = (_Float16)x0.w;
    a[c][4] = (_Float16)x1.x; a[c][5] = (_Float16)x1.y;
    a[c][6] = (_Float16)x1.z; a[c][7] = (_Float16)x1.w;
  }

  f32x4 acc[16];
  #pragma unroll
  for (int n = 0; n < 16; ++n) acc[n] = (f32x4)(0.f);

  #pragma unroll
  for (int c = 0; c < 8; ++c) {
    #pragma unroll
    for (int n = 0; n < 16; ++n) {
      const f16x8 bf = *(const f16x8*)(WT + (size_t)(n*16 + fc)*256 + c*32 + sl*8);
      acc[n] = __builtin_amdgcn_mfma_f32_16x16x32_f16(a[c], bf, acc[n], 0, 0, 0);
    }
  }

  const float alpha = aptr[0];
  float s_[4] = {0.f,0.f,0.f,0.f}, ss[4] = {0.f,0.f,0.f,0.f};
  #pragma unroll
  for (int n = 0; n < 16; ++n) {
    const float bb = bias[b*256 + n*16 + fc];
    #pragma unroll
    for (int r = 0; r < 4; ++r) {
      float x = acc[n][r] + bb;
      x = (x >= 0.f) ? x : alpha*x;
      acc[n][r] = x;
      s_[r] += x; ss[r] += x*x;
    }
  }
  #pragma unroll
  for (int off = 1; off < 16; off <<= 1) {
    #pragma unroll
    for (int r = 0; r < 4; ++r) {
      s_[r] += __shfl_xor(s_[r], off, 16);
      ss[r] += __shfl_xor(ss[r], off, 16);
    }
  }
  float mean[4], rstd[4];
  #pragma unroll
  for (int r = 0; r < 4; ++r) {
    mean[r] = s_[r] * (1.f/256.f);
    const float var = ss[r] * (1.f/256.f) - mean[r]*mean[r];
    rstd[r] = rsqrtf(var + 1e-5f);
  }
  #pragma unroll
  for (int n = 0; n < 16; ++n) {
    const int col = n*16 + fc;
    const float gg = g[col], be = beta[col];
    #pragma unroll
    for (int r = 0; r < 4; ++r) {
      const float o = ((acc[n][r] - mean[r])*rstd[r]*gg + be) * scale;
      out[(size_t)(r0 + sl*4 + r)*256 + col] = (_Float16)o;
    }
  }
}

// ---------------------------------------------------------------------------
// gemm_m1: vgate = sigmoid(vln@Ws + bs) * tanh(vln@Wt + bt), written TRANSPOSED
// to Vt f16 [b][d][t]. 1 wave per block, 16 rows x 256 cols, dual accumulators.
// ---------------------------------------------------------------------------
__global__ __launch_bounds__(64) void gemm_m1(
    const _Float16* __restrict__ vln, const _Float16* __restrict__ WsT,
    const _Float16* __restrict__ WtT, const float* __restrict__ bs,
    const float* __restrict__ bt, _Float16* __restrict__ Vt)
{
  const int lane = threadIdx.x;
  const int fc = lane & 15, sl = lane >> 4;
  const int r0 = blockIdx.x * 16;
  const int b = r0 >> 11, t0 = r0 & 2047;

  f16x8 a[8];
  const _Float16* ap = vln + (size_t)(r0 + fc)*256 + sl*8;
  #pragma unroll
  for (int c = 0; c < 8; ++c) a[c] = *(const f16x8*)(ap + c*32);

  f32x4 aS[16], aT[16];
  #pragma unroll
  for (int n = 0; n < 16; ++n) { aS[n] = (f32x4)(0.f); aT[n] = (f32x4)(0.f); }

  #pragma unroll
  for (int c = 0; c < 8; ++c) {
    #pragma unroll
    for (int n = 0; n < 16; ++n) {
      const f16x8 b1 = *(const f16x8*)(WsT + (size_t)(n*16 + fc)*256 + c*32 + sl*8);
      const f16x8 b2 = *(const f16x8*)(WtT + (size_t)(n*16 + fc)*256 + c*32 + sl*8);
      aS[n] = __builtin_amdgcn_mfma_f32_16x16x32_f16(a[c], b1, aS[n], 0, 0, 0);
      aT[n] = __builtin_amdgcn_mfma_f32_16x16x32_f16(a[c], b2, aT[n], 0, 0, 0);
    }
  }

  #pragma unroll
  for (int n = 0; n < 16; ++n) {
    const int col = n*16 + fc;
    const float b1 = bs[col], b2 = bt[col];
    f16x4 o;
    #pragma unroll
    for (int r = 0; r < 4; ++r) {
      const float v = sigm_(aS[n][r] + b1) * tanh_(aT[n][r] + b2);
      o[r] = (_Float16)v;
    }
    *(f16x4*)(Vt + (size_t)(b*256 + col)*2048 + t0 + sl*4) = o;
  }
}

// ---------------------------------------------------------------------------
// vmeanT: vmean[b][d] += mean over t of Vt[b][d][t]  (atomic partials).
// grid 64 (b x 8 t-chunks) x 256 thr (d).
// ---------------------------------------------------------------------------
__global__ __launch_bounds__(256) void vmeanT(const _Float16* __restrict__ Vt,
                                              float* __restrict__ vmean)
{
  const int b = blockIdx.x >> 3, chunk = blockIdx.x & 7;
  const int d = threadIdx.x;
  const _Float16* p = Vt + (size_t)(b*256 + d)*2048 + chunk*256;
  float s = 0.f;
  #pragma unroll 4
  for (int i = 0; i < 32; ++i) {
    const f16x8 v = *(const f16x8*)(p + i*8);
    #pragma unroll
    for (int j = 0; j < 8; ++j) s += (float)v[j];
  }
  atomicAdd(vmean + b*256 + d, s * (1.f/2048.f));
}

// ---------------------------------------------------------------------------
// attn_mfma: flash attention, f16 MFMA, FIXED-MAX softmax (log2 domain, m=8).
// 2048 waves; wave g -> unit i=g>>1, half=g&1. Per wave: 16 q-rows, 32-col tiles.
// half0 writes unnormalized O to d_out; half1 to pO. l partials to pl.
// ---------------------------------------------------------------------------
__global__ __launch_bounds__(256, 2) void attn_mfma(
    const _Float16* __restrict__ qb, const _Float16* __restrict__ kb,
    const _Float16* __restrict__ Vt, const int* __restrict__ ilen,
    float* __restrict__ pl, float* __restrict__ pO, float* __restrict__ outp)
{
  __shared__ _Float16 Ps[4][512];
  const int w = threadIdx.x >> 6, lane = threadIdx.x & 63;
  const int g = blockIdx.x*4 + w;
  const int i = g >> 1, half = g & 1;
  const int pp = i >> 1, s = i & 1;
  const int qt = s ? 127 - (pp >> 2) : (pp >> 2);
  const int b  = ((pp & 3) << 1) | s;
  const int r0 = qt << 4;
  const int len = ilen[b];
  if (r0 >= len) return;                  // pad-only unit: merge emits vmean
  const int jmax = min(r0 + 16, len);
  const int nt = (jmax + 31) >> 5;
  const int nh = (nt + 1) >> 1;
  const int tb = half ? nh : 0, te = half ? nt : nh;

  const int fc = lane & 15;
  const int sl = lane >> 4;

  f16x8 aq[8];
  {
    const _Float16* qp = qb + (size_t)(b*NT + r0 + fc)*ND + sl*8;
    #pragma unroll
    for (int c = 0; c < 8; ++c) aq[c] = *(const f16x8*)(qp + c*32);
  }

  f32x4 O[16];
  #pragma unroll
  for (int dc = 0; dc < 16; ++dc) O[dc] = (f32x4)(0.f);
  float l_[4] = {0.f, 0.f, 0.f, 0.f};

  const _Float16* kbase = kb + (size_t)b*NT*ND;
  const _Float16* vbase = Vt + (size_t)b*ND*NT;
  _Float16* psw = &Ps[w][0];

  for (int t = tb; t < te; ++t) {
    const int j0 = t << 5;
    // ---- batch-load all 16 K frags (one latency for the group) ----
    f16x8 kk[16];
    const _Float16* kp = kbase + (size_t)(j0 + fc)*ND + sl*8;
    #pragma unroll
    for (int c = 0; c < 8; ++c) {
      kk[c]     = *(const f16x8*)(kp + c*32);
      kk[8 + c] = *(const f16x8*)(kp + (size_t)16*ND + c*32);
    }
    // ---- QK^T: 4 independent MFMA chains ----
    f32x4 S0a = (f32x4)(0.f), S0b = (f32x4)(0.f);
    f32x4 S1a = (f32x4)(0.f), S1b = (f32x4)(0.f);
    #pragma unroll
    for (int c = 0; c < 4; ++c) {
      S0a = __builtin_amdgcn_mfma_f32_16x16x32_f16(aq[c],   kk[c],   S0a, 0, 0, 0);
      S1a = __builtin_amdgcn_mfma_f32_16x16x32_f16(aq[c],   kk[8+c], S1a, 0, 0, 0);
      S0b = __builtin_amdgcn_mfma_f32_16x16x32_f16(aq[4+c], kk[4+c], S0b, 0, 0, 0);
      S1b = __builtin_amdgcn_mfma_f32_16x16x32_f16(aq[4+c], kk[12+c],S1b, 0, 0, 0);
    }
    // ---- batch-issue all 16 V frags (latency hides under softmax) ----
    f16x8 vv[16];
    #pragma unroll
    for (int dc = 0; dc < 16; ++dc)
      vv[dc] = *(const f16x8*)(vbase + (size_t)(dc*16 + fc)*NT + j0 + sl*8);

    // ---- mask + fixed-max exp (no reduce, no rescale) ----
    const int C0 = j0 + fc, C1 = C0 + 16;
    const int Rb = r0 + sl*4;
    float p0[4], p1[4];
    #pragma unroll
    for (int r = 0; r < 4; ++r) {
      const int R = Rb + r;
      const bool okR = (R < len);
      const float x0 = S0a[r] + S0b[r];
      const float x1 = S1a[r] + S1b[r];
      p0[r] = (okR && (C0 <= R) && (x0 != 0.f)) ? exp2f(x0 - MFIX) : 0.f;
      p1[r] = (okR && (C1 <= R) && (x1 != 0.f)) ? exp2f(x1 - MFIX) : 0.f;
      l_[r] += p0[r] + p1[r];
    }
    // ---- P: C-layout -> f16 A-frag via swizzled per-wave LDS (no barrier) ----
    #pragma unroll
    for (int r = 0; r < 4; ++r) {
      const int q = sl*4 + r;
      const int sw = (q & 7) << 3;
      psw[(q*32 + fc) ^ sw]      = (_Float16)p0[r];
      psw[(q*32 + fc + 16) ^ sw] = (_Float16)p1[r];
    }
    const f16x8 pa = *(const f16x8*)&psw[(fc*32 + sl*8) ^ ((fc & 7) << 3)];
    // ---- PV: 16 independent accum chains ----
    #pragma unroll
    for (int dc = 0; dc < 16; ++dc)
      O[dc] = __builtin_amdgcn_mfma_f32_16x16x32_f16(pa, vv[dc], O[dc], 0, 0, 0);
  }

  // ---- reduce l over 16 lanes, store ----
  #pragma unroll
  for (int off = 1; off < 16; off <<= 1) {
    #pragma unroll
    for (int r = 0; r < 4; ++r) l_[r] += __shfl_xor(l_[r], off, 16);
  }
  if (fc == 0) {
    #pragma unroll
    for (int r = 0; r < 4; ++r)
      pl[half*16384 + i*16 + sl*4 + r] = l_[r];
  }
  // ---- write unnormalized O: half0 -> d_out, half1 -> pO ----
  if (half == 0) {
    float* po = outp + (size_t)(b*NT + r0)*ND;
    #pragma unroll
    for (int dc = 0; dc < 16; ++dc) {
      #pragma unroll
      for (int r = 0; r < 4; ++r)
        po[(size_t)(sl*4 + r)*256 + dc*16 + fc] = O[dc][r];
    }
  } else if (tb < te) {
    float* po = pO + (size_t)i * 4096;
    #pragma unroll
    for (int dc = 0; dc < 16; ++dc) {
      #pragma unroll
      for (int r = 0; r < 4; ++r)
        po[(size_t)(sl*4 + r)*256 + dc*16 + fc] = O[dc][r];
    }
  }
}

// ---------------------------------------------------------------------------
// attn_merge: out = (O_half0 + O_half1) / (l0 + l1); pad rows -> vmean.
// ---------------------------------------------------------------------------
__global__ __launch_bounds__(256) void attn_merge(
    const float* __restrict__ pl, const float* __restrict__ pO,
    const float* __restrict__ vmean, const int* __restrict__ ilen,
    float* __restrict__ outp)
{
  const int i = blockIdx.x;
  const int pp = i >> 1, s = i & 1;
  const int qt = s ? 127 - (pp >> 2) : (pp >> 2);
  const int b  = ((pp & 3) << 1) | s;
  const int r0 = qt << 4;
  const int len = ilen[b];
  const int t = threadIdx.x;
  const int row = t >> 4, d0 = (t & 15) << 4;
  const int rowg = r0 + row;
  float4* o4 = (float4*)(outp + (size_t)(b*NT + rowg)*ND + d0);
  if (rowg >= len) {
    const float4* vm4 = (const float4*)(vmean + b*ND + d0);
    #pragma unroll
    for (int ii = 0; ii < 4; ++ii) o4[ii] = vm4[ii];
    return;
  }
  const float l0 = pl[i*16 + row];
  const float l1 = pl[16384 + i*16 + row];
  const float inv = 1.f / (l0 + l1);
  const float4* b4 = (const float4*)(pO + (size_t)i*4096 + row*256 + d0);
  #pragma unroll
  for (int ii = 0; ii < 4; ++ii) {
    float4 a = o4[ii];
    if (l1 > 0.f) {
      const float4 bb = b4[ii];
      a.x += bb.x; a.y += bb.y; a.z += bb.z; a.w += bb.w;
    }
    a.x *= inv; a.y *= inv; a.z *= inv; a.w *= inv;
    o4[ii] = a;
  }
}

// ---------------------------------------------------------------------------
extern "C" void kernel_launch(void* const* d_in, const int* in_sizes, int n_in,
                              void* d_out, int out_size, void* d_ws, size_t ws_size,
                              hipStream_t stream) {
  const float* query = (const float*)d_in[0];
  const float* value = (const float*)d_in[1];
  const float* aux   = (const float*)d_in[2];
  const int*   ilen  = (const int*)  d_in[3];
  const float* Wql = (const float*)d_in[4];
  const float* bql = (const float*)d_in[5];
  const float* Wq  = (const float*)d_in[6];
  const float* bq  = (const float*)d_in[7];
  const float* aq  = (const float*)d_in[8];
  const float* gq  = (const float*)d_in[9];
  const float* btq = (const float*)d_in[10];
  const float* Wk  = (const float*)d_in[11];
  const float* bk  = (const float*)d_in[12];
  const float* ak  = (const float*)d_in[13];
  const float* gk  = (const float*)d_in[14];
  const float* btk = (const float*)d_in[15];
  const float* Wv  = (const float*)d_in[16];
  const float* bv  = (const float*)d_in[17];
  const float* av  = (const float*)d_in[18];
  const float* gv  = (const float*)d_in[19];
  const float* btv = (const float*)d_in[20];
  const float* Ws  = (const float*)d_in[21];
  const float* bs  = (const float*)d_in[22];
  const float* Wt  = (const float*)d_in[23];
  const float* bt  = (const float*)d_in[24];

  float* wsf = (float*)d_ws;
  _Float16* qbuf = (_Float16*)(wsf);                 // 8 MB
  _Float16* kbuf = (_Float16*)(wsf + 2097152);       // 8 MB
  _Float16* vln  = (_Float16*)(wsf + 4194304);       // 8 MB
  _Float16* Vt   = (_Float16*)(wsf + 6291456);       // 8 MB
  float* pO    = wsf + 8388608;                      // 16 MB (1024 x 4096)
  float* Wcq   = wsf + 12582912;                     // 256 KB
  _Float16* WT = (_Float16*)(wsf + 12648448);        // 5 x 128 KB f16
  float* biasq = wsf + 12812288;
  float* biask = biasq + 2048;
  float* biasv = biask + 2048;
  float* vmean = biasv + 2048;
  float* pl    = vmean + 2048;                       // 2 x 1024 x 16

  _Float16* WcqT = WT;
  _Float16* WkT  = WT + 65536;
  _Float16* WvT  = WT + 2*65536;
  _Float16* WsT  = WT + 3*65536;
  _Float16* WtT  = WT + 4*65536;

  prep_kernel<<<dim3(264), dim3(256), 0, stream>>>(
      Wql, bql, Wq, bq, Wk, bk, Wv, bv, aux, Wcq, biasq, biask, biasv, vmean);

  transW<<<dim3(4,4,5), dim3(256), 0, stream>>>(Wcq, Wk, Wv, Ws, Wt, WT);

  gemm_m0<<<dim3(1024), dim3(64), 0, stream>>>(
      query, WcqT, biasq, aq, gq, btq, qbuf, QSCALE);
  gemm_m0<<<dim3(1024), dim3(64), 0, stream>>>(
      value, WkT, biask, ak, gk, btk, kbuf, 1.0f);
  gemm_m0<<<dim3(1024), dim3(64), 0, stream>>>(
      value, WvT, biasv, av, gv, btv, vln, 1.0f);
  gemm_m1<<<dim3(1024), dim3(64), 0, stream>>>(
      vln, WsT, WtT, bs, bt, Vt);

  vmeanT<<<dim3(64), dim3(256), 0, stream>>>(Vt, vmean);

  attn_mfma<<<dim3(512), dim3(256), 0, stream>>>(
      qbuf, kbuf, Vt, ilen, pl, pO, (float*)d_out);

  attn_merge<<<dim3(1024), dim3(256), 0, stream>>>(
      pl, pO, vmean, ilen, (float*)d_out);
}